// Round 6
// baseline (22457.037 us; speedup 1.0000x reference)
//
#include <hip/hip_runtime.h>
#include <math.h>

#define EPSF 1e-5f

// DPP helper: v += value from lane (i - N) within the 16-lane DPP row (0 if OOB)
template<int CTRL>
__device__ __forceinline__ float dpp_add(float v) {
    int s = __builtin_amdgcn_update_dpp(0, __float_as_int(v), CTRL, 0xf, 0xf, true);
    return v + __int_as_float(s);
}
// pair sum: v + partner-lane value (quad_perm [1,0,3,2])
__device__ __forceinline__ float pair_sum(float v) {
    int s = __builtin_amdgcn_update_dpp(0, __float_as_int(v), 0xB1, 0xf, 0xf, true);
    return v + __int_as_float(s);
}

// ---------------- prep: weight transposes + bool-dtype detect ----------------
__global__ __launch_bounds__(256) void k_prep(
    const float* __restrict__ Wih,
    const float* __restrict__ W2, const float* __restrict__ W3,
    const unsigned char* __restrict__ fmask,
    float* __restrict__ WxT,
    float* __restrict__ W2T, float* __restrict__ W3T, int* __restrict__ flag)
{
    int idx = blockIdx.x * 256 + threadIdx.x;
    if (idx < 105984) {                 // Wih[768][138] x-part -> WxT[128][768]
        int j = idx / 138, k = idx % 138;
        if (k < 128) WxT[k * 768 + j] = Wih[idx];
    }
    if (idx < 409600) {                 // W[co][ci][5][5] -> WT[tap][ci][co]
        int co = idx / 3200, r = idx % 3200;
        int ci = r / 25, tap = r % 25;
        int dst = (tap * 128 + ci) * 128 + co;
        W2T[dst] = W2[idx];
        W3T[dst] = W3[idx];
    }
    if (idx == 0) {                     // bool stored as int32? bytes 1,2,3 of each word all zero
        int nz = 0;
        for (int i = 0; i < 4096; i++) if ((i & 3) != 0) nz |= fmask[i];
        *flag = nz ? 0 : 1;
    }
}

// ---------------- conv1: [32,1,1024,40] -> X1[b][t][m1(8)][co(128)] ----------------
__global__ __launch_bounds__(256) void k_conv1(
    const float* __restrict__ X, const float* __restrict__ W1,
    const float* __restrict__ bb, const float* __restrict__ gg,
    const float* __restrict__ be, const float* __restrict__ mm_,
    const float* __restrict__ vv, float* __restrict__ X1)
{
    __shared__ __align__(16) float xs[8][44];
    __shared__ __align__(16) float ws[25][128];
    __shared__ float sc[128], sh[128];
    int bid = blockIdx.x;
    int b = bid >> 8, t0 = (bid & 255) << 2;
    int tid = threadIdx.x;
    for (int e = tid; e < 8 * 44; e += 256) {
        int tt = e / 44, mm = e % 44;
        int gt = t0 + tt - 2, gm = mm - 2;
        float val = 0.f;
        if (gt >= 0 && gt < 1024 && gm >= 0 && gm < 40)
            val = X[(b * 1024 + gt) * 40 + gm];
        xs[tt][mm] = val;
    }
    for (int e = tid; e < 3200; e += 256) {
        int tap = e >> 7, co = e & 127;
        ws[tap][co] = W1[co * 25 + tap];
    }
    if (tid < 128) {
        float s = gg[tid] / sqrtf(vv[tid] + EPSF);
        sc[tid] = s;
        sh[tid] = (bb[tid] - mm_[tid]) * s + be[tid];
    }
    __syncthreads();
    int cog = tid >> 5;          // 8 groups x 16 co
    int m1i = (tid >> 2) & 7;    // pooled mel
    int tp  = tid & 3;           // t'
    int co0 = cog * 16;
    float val[5][16];
#pragma unroll
    for (int p = 0; p < 5; p++)
#pragma unroll
        for (int i = 0; i < 16; i++) val[p][i] = 0.f;
#pragma unroll
    for (int dt = 0; dt < 5; dt++) {
#pragma unroll
        for (int dm = 0; dm < 5; dm++) {
            float w[16];
#pragma unroll
            for (int i = 0; i < 16; i += 4)
                *(float4*)&w[i] = *(const float4*)&ws[dt * 5 + dm][co0 + i];
#pragma unroll
            for (int p = 0; p < 5; p++) {
                float x = xs[tp + dt][m1i * 5 + p + dm];
#pragma unroll
                for (int i = 0; i < 16; i++) val[p][i] = fmaf(x, w[i], val[p][i]);
            }
        }
    }
    float outv[16];
#pragma unroll
    for (int i = 0; i < 16; i++) {
        float s = sc[co0 + i], h = sh[co0 + i];
        float mx = 0.f;
#pragma unroll
        for (int p = 0; p < 5; p++) {
            float y = fmaf(val[p][i], s, h);
            y = fmaxf(y, 0.f);
            mx = fmaxf(mx, y);
        }
        outv[i] = mx;
    }
    float* dst = &X1[(((long)(b * 1024 + t0 + tp)) * 8 + m1i) * 128 + co0];
#pragma unroll
    for (int i = 0; i < 16; i += 4) *(float4*)&dst[i] = *(float4*)&outv[i];
}

// ---------------- conv2: X1 -> X2[b][t][m2(2)][co(128)] ----------------
__global__ __launch_bounds__(256) void k_conv2(
    const float* __restrict__ X1, const float* __restrict__ W2T,
    const float* __restrict__ bb, const float* __restrict__ gg,
    const float* __restrict__ be, const float* __restrict__ mm_,
    const float* __restrict__ vv, float* __restrict__ X2)
{
    __shared__ __align__(16) float xs[20][33][12];  // [t''][ci(pad)][m']
    __shared__ __align__(16) float ws[5][32][64];   // [dm][ci][co]
    __shared__ float sc[64], sh[64];
    int bid = blockIdx.x;
    int coh = bid & 1, t0 = ((bid >> 1) & 63) << 4, b = bid >> 7;
    int co_base = coh * 64;
    int tid = threadIdx.x;
    int tp = tid & 15, cog = tid >> 4;   // 16 t' x 16 cog(4 co each)
    if (tid < 64) {
        int co = co_base + tid;
        float s = gg[co] / sqrtf(vv[co] + EPSF);
        sc[tid] = s;
        sh[tid] = (bb[co] - mm_[co]) * s + be[co];
    }
    float acc[4][8];
#pragma unroll
    for (int c = 0; c < 4; c++)
#pragma unroll
        for (int m = 0; m < 8; m++) acc[c][m] = 0.f;

    for (int cc = 0; cc < 4; cc++) {
        __syncthreads();
        for (int e = tid; e < 20 * 32 * 12; e += 256) {
            int ci = e & 31, mm = (e >> 5) % 12, tt = e / 384;
            int gt = t0 + tt - 2, gm = mm - 2;
            float v = 0.f;
            if (gt >= 0 && gt < 1024 && gm >= 0 && gm < 8)
                v = X1[(((long)(b * 1024 + gt)) * 8 + gm) * 128 + cc * 32 + ci];
            xs[tt][ci][mm] = v;
        }
        for (int dt = 0; dt < 5; dt++) {
            __syncthreads();
            for (int e = tid; e < 5 * 32 * 64; e += 256) {
                int co = e & 63, ci = (e >> 6) & 31, dm = e >> 11;
                ws[dm][ci][co] = W2T[((dt * 5 + dm) * 128 + cc * 32 + ci) * 128 + co_base + co];
            }
            __syncthreads();
            for (int ci = 0; ci < 32; ci++) {
                float x[12];
                *(float4*)&x[0] = *(const float4*)&xs[tp + dt][ci][0];
                *(float4*)&x[4] = *(const float4*)&xs[tp + dt][ci][4];
                *(float4*)&x[8] = *(const float4*)&xs[tp + dt][ci][8];
#pragma unroll
                for (int dm = 0; dm < 5; dm++) {
                    float w[4];
                    *(float4*)&w[0] = *(const float4*)&ws[dm][ci][cog * 4];
#pragma unroll
                    for (int c = 0; c < 4; c++)
#pragma unroll
                        for (int m = 0; m < 8; m++)
                            acc[c][m] = fmaf(w[c], x[m + dm], acc[c][m]);
                }
            }
        }
    }
    int t = t0 + tp;
#pragma unroll
    for (int m2 = 0; m2 < 2; m2++) {
        float4 ov;
        float* po = (float*)&ov;
#pragma unroll
        for (int c = 0; c < 4; c++) {
            float s = sc[cog * 4 + c], h = sh[cog * 4 + c];
            float mx = 0.f;
#pragma unroll
            for (int q = 0; q < 4; q++) {
                float y = fmaf(acc[c][m2 * 4 + q], s, h);
                y = fmaxf(y, 0.f);
                mx = fmaxf(mx, y);
            }
            po[c] = mx;
        }
        *(float4*)&X2[(((long)(b * 1024 + t)) * 2 + m2) * 128 + co_base + cog * 4] = ov;
    }
}

// ---------------- conv3: X2 -> F[t][b][co] (mel pooled to 1) ----------------
__global__ __launch_bounds__(256) void k_conv3(
    const float* __restrict__ X2, const float* __restrict__ W3T,
    const float* __restrict__ bb, const float* __restrict__ gg,
    const float* __restrict__ be, const float* __restrict__ mm_,
    const float* __restrict__ vv, float* __restrict__ F)
{
    __shared__ __align__(16) float xs[20][33][8];   // [t''][ci(pad)][m'] (m' 0..5 used)
    __shared__ __align__(16) float ws[5][32][64];
    __shared__ float sc[64], sh[64];
    int bid = blockIdx.x;
    int coh = bid & 1, t0 = ((bid >> 1) & 63) << 4, b = bid >> 7;
    int co_base = coh * 64;
    int tid = threadIdx.x;
    int tp = tid & 15, cog = tid >> 4;
    if (tid < 64) {
        int co = co_base + tid;
        float s = gg[co] / sqrtf(vv[co] + EPSF);
        sc[tid] = s;
        sh[tid] = (bb[co] - mm_[co]) * s + be[co];
    }
    float acc[4][2];
#pragma unroll
    for (int c = 0; c < 4; c++) { acc[c][0] = 0.f; acc[c][1] = 0.f; }

    for (int cc = 0; cc < 4; cc++) {
        __syncthreads();
        for (int e = tid; e < 20 * 32 * 8; e += 256) {
            int ci = e & 31, mm = (e >> 5) & 7, tt = e >> 8;
            int gt = t0 + tt - 2, gm = mm - 2;
            float v = 0.f;
            if (gt >= 0 && gt < 1024 && (gm == 0 || gm == 1))
                v = X2[(((long)(b * 1024 + gt)) * 2 + gm) * 128 + cc * 32 + ci];
            xs[tt][ci][mm] = v;
        }
        for (int dt = 0; dt < 5; dt++) {
            __syncthreads();
            for (int e = tid; e < 5 * 32 * 64; e += 256) {
                int co = e & 63, ci = (e >> 6) & 31, dm = e >> 11;
                ws[dm][ci][co] = W3T[((dt * 5 + dm) * 128 + cc * 32 + ci) * 128 + co_base + co];
            }
            __syncthreads();
            for (int ci = 0; ci < 32; ci++) {
                float x[8];
                *(float4*)&x[0] = *(const float4*)&xs[tp + dt][ci][0];
                *(float4*)&x[4] = *(const float4*)&xs[tp + dt][ci][4];
#pragma unroll
                for (int dm = 0; dm < 5; dm++) {
                    float w[4];
                    *(float4*)&w[0] = *(const float4*)&ws[dm][ci][cog * 4];
#pragma unroll
                    for (int c = 0; c < 4; c++) {
                        acc[c][0] = fmaf(w[c], x[0 + dm], acc[c][0]);
                        acc[c][1] = fmaf(w[c], x[1 + dm], acc[c][1]);
                    }
                }
            }
        }
    }
    float4 ov;
    float* po = (float*)&ov;
#pragma unroll
    for (int c = 0; c < 4; c++) {
        float s = sc[cog * 4 + c], h = sh[cog * 4 + c];
        float y0 = fmaxf(fmaf(acc[c][0], s, h), 0.f);
        float y1 = fmaxf(fmaf(acc[c][1], s, h), 0.f);
        po[c] = fmaxf(y0, y1);
    }
    *(float4*)&F[((long)(t0 + tp) * 32 + b) * 128 + co_base + cog * 4] = ov;
}

// ---------------- Gx = F @ Wihx.T + bih : [32768,128]x[128,768] ----------------
__global__ __launch_bounds__(256) void k_gemm(
    const float* __restrict__ F, const float* __restrict__ WxT,
    const float* __restrict__ bih, float* __restrict__ Gx)
{
    __shared__ __align__(16) float Fs[64][33];
    __shared__ __align__(16) float Ws[32][256];
    int bid = blockIdx.x;
    int jt = bid % 3, tb0 = (bid / 3) * 64;
    int tid = threadIdx.x;
    int tx = tid & 31, ty = tid >> 5;
    float acc[8][8];
#pragma unroll
    for (int i = 0; i < 8; i++)
#pragma unroll
        for (int j = 0; j < 8; j++) acc[i][j] = 0.f;
    for (int cc = 0; cc < 4; cc++) {
        __syncthreads();
        for (int e = tid; e < 64 * 32; e += 256) {
            int ci = e & 31, i = e >> 5;
            Fs[i][ci] = F[(long)(tb0 + i) * 128 + cc * 32 + ci];
        }
        for (int e = tid; e < 32 * 256; e += 256) {
            int jj = e & 255, ci = e >> 8;
            Ws[ci][jj] = WxT[(cc * 32 + ci) * 768 + jt * 256 + jj];
        }
        __syncthreads();
        for (int ci = 0; ci < 32; ci++) {
            float a[8], w[8];
#pragma unroll
            for (int i = 0; i < 8; i++) a[i] = Fs[ty * 8 + i][ci];
            *(float4*)&w[0] = *(const float4*)&Ws[ci][tx * 8];
            *(float4*)&w[4] = *(const float4*)&Ws[ci][tx * 8 + 4];
#pragma unroll
            for (int i = 0; i < 8; i++)
#pragma unroll
                for (int j = 0; j < 8; j++) acc[i][j] = fmaf(a[i], w[j], acc[i][j]);
        }
    }
    float bj[8];
#pragma unroll
    for (int j = 0; j < 8; j++) bj[j] = bih[jt * 256 + tx * 8 + j];
#pragma unroll
    for (int i = 0; i < 8; i++) {
        float o[8];
#pragma unroll
        for (int j = 0; j < 8; j++) o[j] = acc[i][j] + bj[j];
        float* dst = &Gx[(long)(tb0 + ty * 8 + i) * 768 + jt * 256 + tx * 8];
        *(float4*)&dst[0] = *(float4*)&o[0];
        *(float4*)&dst[4] = *(float4*)&o[4];
    }
}

// ================== GRU, 6 WGs per batch, Whh LDS-resident ==================
// WG role r of batch b holds Whh rows [r*128, r*128+128) in LDS (131.6 KB, stride
// 257 => ds_read_b32 2-way banks = free). Inner loop has ZERO global weight loads
// (allocator/latency-proof; R2-R5 all died on the global-load path). Per step each
// WG computes its 128 row-dots, all-to-all exchanges gsum slices through a
// double-buffered global buffer with agent-scope release/acquire flags (the
// cross-XCD-correct pattern), then EVERY WG redundantly computes the identical
// gate/h/tf update locally -- no h broadcast round-trip.
__global__ __launch_bounds__(256) void k_gru6(
    const float* __restrict__ Whh, const float* __restrict__ Gx,
    const float* __restrict__ Wih, const float* __restrict__ bhh_g,
    const float* __restrict__ Wf, const float* __restrict__ bf_g,
    const float* __restrict__ targets, const unsigned char* __restrict__ fmask,
    const int* __restrict__ flag,
    float* __restrict__ gsumG, int* __restrict__ fA, int* __restrict__ fR,
    float* __restrict__ out)
{
    extern __shared__ float lds[];
    float* wL  = lds;                    // 128*257 = 32896 floats
    float* hL  = lds + 128 * 257;        // 256
    float* tfl = hL + 256;               // 16
    const int bid = blockIdx.x;
    const int b = bid / 6, role = bid - b * 6;
    const int tid = threadIdx.x;
    const int R0 = role * 128;

    // stage this WG's 128 Whh rows into LDS (once)
    for (int e = tid; e < 128 * 256; e += 256) {
        int r = e >> 8, c = e & 255;
        wL[r * 257 + c] = Whh[(R0 + r) * 256 + c];
    }
    // gate constants (identical in every WG)
    float wtf0[10], wtf1[10], wtf2[10];
#pragma unroll
    for (int c = 0; c < 10; c++) {
        wtf0[c] = Wih[tid * 138 + 128 + c];
        wtf1[c] = Wih[(tid + 256) * 138 + 128 + c];
        wtf2[c] = Wih[(tid + 512) * 138 + 128 + c];
    }
    const float bh0 = bhh_g[tid], bh1 = bhh_g[tid + 256], bh2 = bhh_g[tid + 512];
    const bool isProj = (tid < 160);
    const int oc = tid >> 4, seg = tid & 15;
    float wf16[16];
#pragma unroll
    for (int i = 0; i < 16; i++) wf16[i] = 0.f;
    if (isProj) {
#pragma unroll
        for (int i = 0; i < 16; i++) wf16[i] = Wf[oc * 256 + seg * 16 + i];
    }
    const float bfc = isProj ? bf_g[oc] : 0.f;
    const bool isWr = isProj && (seg == 15);
    const int int32mode = flag[0];

    hL[tid] = 0.f;
    if (tid < 16) tfl[tid] = 0.f;
    __syncthreads();

    const int rg = tid >> 1, half = tid & 1;      // 2 threads per row, 128-col halves
    float* gslice = gsumG + (long)b * 2 * 768;    // [p][768]
    int* pfA = fA + b;
    int* pfR = fR + b;
    float hold = 0.f;                             // h[tid], replicated in all 6 WGs

    for (int t = 0; t < 1024; t++) {
        const int p = t & 1;
        // writers of buffer p must wait until step t-2's readers are done
        if (tid == 0 && t >= 2) {
            int tgtv = 6 * (t - 1);
            while (__hip_atomic_load(pfR, __ATOMIC_ACQUIRE, __HIP_MEMORY_SCOPE_AGENT) < tgtv)
                __builtin_amdgcn_s_sleep(2);
        }
        // prefetch step inputs (consumed after the exchange)
        const float* gx = &Gx[((long)t * 32 + b) * 768];
        float gxr = gx[tid], gxz = gx[tid + 256], gxn = gx[tid + 512];
        float tgt = 0.f; int fmv = 0;
        if (isWr) {
            tgt = targets[((long)b * 1024 + t) * 10 + oc];
            fmv = int32mode ? ((const int*)fmask)[t * 32 + b] : (int)fmask[t * 32 + b];
        }

        // ---- local row dots from LDS weights (conflict-free) ----
        float acc = 0.f;
        const float* wrow = wL + rg * 257 + half * 128;
        const float4* hp = (const float4*)(hL + half * 128);
#pragma unroll
        for (int i2 = 0; i2 < 32; i2++) {
            float4 hv = hp[i2];
            acc = fmaf(wrow[i2 * 4 + 0], hv.x, acc);
            acc = fmaf(wrow[i2 * 4 + 1], hv.y, acc);
            acc = fmaf(wrow[i2 * 4 + 2], hv.z, acc);
            acc = fmaf(wrow[i2 * 4 + 3], hv.w, acc);
        }
        float s = pair_sum(acc);      // half0+half1; valid on even lane
        __syncthreads();              // A: join fR-spin + dots

        if (half == 0)
            __hip_atomic_store(&gslice[p * 768 + R0 + rg], s,
                               __ATOMIC_RELAXED, __HIP_MEMORY_SCOPE_AGENT);
        __syncthreads();              // B: all slice stores issued & drained (vmcnt0)

        if (tid == 0) {
            __hip_atomic_fetch_add(pfA, 1, __ATOMIC_RELEASE, __HIP_MEMORY_SCOPE_AGENT);
            int tgtv = 6 * (t + 1);
            while (__hip_atomic_load(pfA, __ATOMIC_ACQUIRE, __HIP_MEMORY_SCOPE_AGENT) < tgtv)
                __builtin_amdgcn_s_sleep(2);
        }
        __syncthreads();              // C: all 6 slices visible

        float ar = __hip_atomic_load(&gslice[p * 768 + tid],
                                     __ATOMIC_RELAXED, __HIP_MEMORY_SCOPE_AGENT) + bh0;
        float az = __hip_atomic_load(&gslice[p * 768 + 256 + tid],
                                     __ATOMIC_RELAXED, __HIP_MEMORY_SCOPE_AGENT) + bh1;
        float an = __hip_atomic_load(&gslice[p * 768 + 512 + tid],
                                     __ATOMIC_RELAXED, __HIP_MEMORY_SCOPE_AGENT) + bh2;

        // ---- gate (replicated; bitwise-identical in all 6 WGs) ----
        float gr = gxr, gz = gxz, gn = gxn;
#pragma unroll
        for (int c = 0; c < 10; c++) {
            float tv = tfl[c];
            gr = fmaf(tv, wtf0[c], gr);
            gz = fmaf(tv, wtf1[c], gz);
            gn = fmaf(tv, wtf2[c], gn);
        }
        float r = 1.0f / (1.0f + expf(-(gr + ar)));
        float z = 1.0f / (1.0f + expf(-(gz + az)));
        float n = tanhf(fmaf(r, an, gn));
        float hnew = (1.0f - z) * n + z * hold;
        hold = hnew;
        hL[tid] = hnew;
        __syncthreads();              // D: hL ready; gsum loads drained
        if (tid == 0)
            __hip_atomic_fetch_add(pfR, 1, __ATOMIC_RELEASE, __HIP_MEMORY_SCOPE_AGENT);

        // ---- out projection + tf update (replicated; role0 writes out) ----
        if (isProj) {
            const float* hh = &hL[seg * 16];
            float sp = 0.f;
#pragma unroll
            for (int i = 0; i < 16; i++) sp = fmaf(wf16[i], hh[i], sp);
            sp = dpp_add<0x111>(sp);
            sp = dpp_add<0x112>(sp);
            sp = dpp_add<0x114>(sp);
            sp = dpp_add<0x118>(sp);  // lane seg==15 holds full sum
            if (isWr) {
                float o = sp + bfc;
                if (role == 0) out[((long)b * 1024 + t) * 10 + oc] = o;
                float pred = (o > 0.f) ? 1.f : 0.f;
                tfl[oc] = fmv ? tgt : pred;
            }
        }
        __syncthreads();              // E: tfl ready for next gate
    }
}

// ---------------- fallback GRU (R5): used only if >64KB dynamic LDS rejected ---------
__global__ __attribute__((amdgpu_waves_per_eu(4, 4))) __launch_bounds__(1024) void k_gru_fb(
    const float* __restrict__ Whh, const float* __restrict__ Gx,
    const float* __restrict__ Wih, const float* __restrict__ bhh_g,
    const float* __restrict__ Wf, const float* __restrict__ bf_g,
    const float* __restrict__ targets, const unsigned char* __restrict__ fmask,
    const int* __restrict__ flag, float* __restrict__ out)
{
    __shared__ __align__(16) float hq[8 * 268];
    __shared__ float gsum[768];
    __shared__ float tfl[16];
    __shared__ float wtfL[30 * 256];
    __shared__ float WfL[2560];
    const int b = blockIdx.x, tid = threadIdx.x;
    const int kgs = tid & 15, rg = tid >> 4;
    const bool isGate = (tid < 256);
    float bh0 = 0.f, bh1 = 0.f, bh2 = 0.f, hold = 0.f;
    if (isGate) { bh0 = bhh_g[tid]; bh1 = bhh_g[tid + 256]; bh2 = bhh_g[tid + 512]; }
    const bool isProj = (tid >= 256 && tid < 416);
    const int oc = (tid - 256) >> 4, seg = tid & 15;
    float bfc = isProj ? bf_g[oc] : 0.f;
    const bool isWr = isProj && (seg == 15);
    const int int32mode = flag[0];
    for (int e = tid; e < 7680; e += 1024) {
        int cp = e >> 8, jj = e & 255;
        int g = cp / 10, c = cp - g * 10;
        wtfL[e] = Wih[(g * 256 + jj) * 138 + 128 + c];
    }
    for (int e = tid; e < 2560; e += 1024) WfL[e] = Wf[e];
    for (int e = tid; e < 8 * 268; e += 1024) hq[e] = 0.f;
    if (tid < 16) tfl[tid] = 0.f;
    __syncthreads();
    const float4* hbase = (const float4*)&hq[(kgs >> 1) * 268 + kgs * 16];
    const float4* wbase = ((const float4*)Whh) + kgs * 4;
    int tr = 0;
    for (int t = 0; t < 1024; t++) {
        float gxr = 0.f, gxz = 0.f, gxn = 0.f;
        if (isGate) {
            const float* gx = &Gx[((long)t * 32 + b) * 768];
            gxr = gx[tid]; gxz = gx[tid + 256]; gxn = gx[tid + 512];
        }
        float tgt = 0.f; int fmv = 0;
        if (isWr) {
            tgt = targets[((long)b * 1024 + t) * 10 + oc];
            fmv = int32mode ? ((const int*)fmask)[t * 32 + b] : (int)fmask[t * 32 + b];
        }
        float4 hv[4];
#pragma unroll
        for (int q = 0; q < 4; q++) hv[q] = hbase[q];
        float4 sb[3][4];
#pragma unroll
        for (int pq = 0; pq < 3; pq++) {
            int ro = tr + pq; if (ro >= 12) ro -= 12;
            const float4* wp = wbase + (rg * 12 + ro) * 64;
#pragma unroll
            for (int q = 0; q < 4; q++) sb[pq][q] = wp[q];
        }
#pragma unroll
        for (int i = 0; i < 12; i++) {
            const int sl = i % 3;
            int ro = tr + i; if (ro >= 12) ro -= 12;
            float s = 0.f;
#pragma unroll
            for (int q = 0; q < 4; q++) {
                s = fmaf(sb[sl][q].x, hv[q].x, s);
                s = fmaf(sb[sl][q].y, hv[q].y, s);
                s = fmaf(sb[sl][q].z, hv[q].z, s);
                s = fmaf(sb[sl][q].w, hv[q].w, s);
            }
            if (i + 3 < 12) {
                int rn = tr + i + 3; if (rn >= 12) rn -= 12;
                const float4* wp = wbase + (rg * 12 + rn) * 64;
#pragma unroll
                for (int q = 0; q < 4; q++) sb[sl][q] = wp[q];
            }
            s = dpp_add<0x111>(s);
            s = dpp_add<0x112>(s);
            s = dpp_add<0x114>(s);
            s = dpp_add<0x118>(s);
            if (kgs == 15) gsum[rg * 12 + ro] = s;
        }
        __syncthreads();
        if (isGate) {
            float gr = gxr, gz = gxz, gn = gxn;
#pragma unroll
            for (int c = 0; c < 10; c++) {
                float tv = tfl[c];
                gr = fmaf(tv, wtfL[c * 256 + tid], gr);
                gz = fmaf(tv, wtfL[(10 + c) * 256 + tid], gz);
                gn = fmaf(tv, wtfL[(20 + c) * 256 + tid], gn);
            }
            float ar = gsum[tid] + bh0;
            float az = gsum[tid + 256] + bh1;
            float an = gsum[tid + 512] + bh2;
            float r = 1.0f / (1.0f + expf(-(gr + ar)));
            float z = 1.0f / (1.0f + expf(-(gz + az)));
            float n = tanhf(fmaf(r, an, gn));
            float hnew = (1.0f - z) * n + z * hold;
            hold = hnew;
#pragma unroll
            for (int c = 0; c < 8; c++) hq[c * 268 + tid] = hnew;
        }
        __syncthreads();
        if (isProj) {
            const float* hp2 = &hq[(seg >> 1) * 268 + seg * 16];
            const float* wfp = &WfL[oc * 256 + seg * 16];
            float s = 0.f;
#pragma unroll
            for (int i = 0; i < 16; i++) s = fmaf(wfp[i], hp2[i], s);
            s = dpp_add<0x111>(s);
            s = dpp_add<0x112>(s);
            s = dpp_add<0x114>(s);
            s = dpp_add<0x118>(s);
            if (isWr) {
                float o = s + bfc;
                out[((long)b * 1024 + t) * 10 + oc] = o;
                float pred = (o > 0.f) ? 1.f : 0.f;
                tfl[oc] = fmv ? tgt : pred;
            }
        }
        tr++; if (tr == 12) tr = 0;
    }
}

extern "C" void kernel_launch(void* const* d_in, const int* in_sizes, int n_in,
                              void* d_out, int out_size, void* d_ws, size_t ws_size,
                              hipStream_t stream) {
    (void)in_sizes; (void)n_in; (void)out_size; (void)ws_size;
    const float* features = (const float*)d_in[0];
    const float* targets  = (const float*)d_in[1];
    const unsigned char* fmask = (const unsigned char*)d_in[2];
    const float* W1  = (const float*)d_in[3];
    const float* b1  = (const float*)d_in[4];
    const float* g1  = (const float*)d_in[5];
    const float* be1 = (const float*)d_in[6];
    const float* m1  = (const float*)d_in[7];
    const float* v1  = (const float*)d_in[8];
    const float* W2  = (const float*)d_in[9];
    const float* b2  = (const float*)d_in[10];
    const float* g2  = (const float*)d_in[11];
    const float* be2 = (const float*)d_in[12];
    const float* m2  = (const float*)d_in[13];
    const float* v2  = (const float*)d_in[14];
    const float* W3  = (const float*)d_in[15];
    const float* b3  = (const float*)d_in[16];
    const float* g3  = (const float*)d_in[17];
    const float* be3 = (const float*)d_in[18];
    const float* m3  = (const float*)d_in[19];
    const float* v3  = (const float*)d_in[20];
    const float* Wih = (const float*)d_in[21];
    const float* Whh = (const float*)d_in[22];
    const float* bih = (const float*)d_in[23];
    const float* bhh = (const float*)d_in[24];
    const float* Wf  = (const float*)d_in[25];
    const float* bf  = (const float*)d_in[26];

    char* w = (char*)d_ws;
    float* WxT = (float*)(w + 786432);                  // 393216 B
    float* W2T = (float*)(w + 1179648);                 // 1638400 B
    float* W3T = (float*)(w + 2818048);                 // 1638400 B
    int*   flag = (int*)(w + 4456448);                  // 512 B slot
    float* X1  = (float*)(w + 4456960);                 // 128 MB; reused as Gx after conv2
    float* Gx  = X1;                                    // 100663296 B actually used
    // comm region: inside X1 allocation but PAST Gx end; valid only after conv2
    const size_t CB = 4456960 + 100663296;
    float* gsumG = (float*)(w + CB);                    // 32*2*768*4 = 196608 B
    int*   fA    = (int*)(w + CB + 196608);             // 128 B
    int*   fR    = (int*)(w + CB + 196736);             // 128 B
    float* X2  = (float*)(w + 4456960 + 134217728);     // 32 MB
    float* F   = (float*)(w + 4456960 + 134217728 + 33554432); // 16 MB
    float* out = (float*)d_out;

    const int GRU_LDS = (128 * 257 + 256 + 16) * 4;     // 132672 B
    hipError_t rc = hipFuncSetAttribute((const void*)k_gru6,
        hipFuncAttributeMaxDynamicSharedMemorySize, GRU_LDS);

    k_prep<<<1600, 256, 0, stream>>>(Wih, W2, W3, fmask, WxT, W2T, W3T, flag);
    k_conv1<<<8192, 256, 0, stream>>>(features, W1, b1, g1, be1, m1, v1, X1);
    k_conv2<<<4096, 256, 0, stream>>>(X1, W2T, b2, g2, be2, m2, v2, X2);
    hipMemsetAsync(w + CB + 196608, 0, 256, stream);    // zero fA/fR (X1 dead now)
    k_conv3<<<4096, 256, 0, stream>>>(X2, W3T, b3, g3, be3, m3, v3, F);
    k_gemm<<<1536, 256, 0, stream>>>(F, WxT, bih, Gx);
    if (rc == hipSuccess) {
        k_gru6<<<192, 256, GRU_LDS, stream>>>(Whh, Gx, Wih, bhh, Wf, bf,
                                              targets, fmask, flag, gsumG, fA, fR, out);
    } else {
        k_gru_fb<<<32, 1024, 0, stream>>>(Whh, Gx, Wih, bhh, Wf, bf,
                                          targets, fmask, flag, out);
    }
}

// Round 7
// 17756.023 us; speedup vs baseline: 1.2648x; 1.2648x over previous
//
#include <hip/hip_runtime.h>
#include <math.h>

#define EPSF 1e-5f

typedef __attribute__((ext_vector_type(4))) float f4;

// DPP helper: v += value from lane (i - N) within the 16-lane DPP row (0 if OOB)
template<int CTRL>
__device__ __forceinline__ float dpp_add(float v) {
    int s = __builtin_amdgcn_update_dpp(0, __float_as_int(v), CTRL, 0xf, 0xf, true);
    return v + __int_as_float(s);
}

// ---------------- prep: weight transposes + bool-dtype detect ----------------
__global__ __launch_bounds__(256) void k_prep(
    const float* __restrict__ Wih,
    const float* __restrict__ W2, const float* __restrict__ W3,
    const unsigned char* __restrict__ fmask,
    float* __restrict__ WxT,
    float* __restrict__ W2T, float* __restrict__ W3T, int* __restrict__ flag)
{
    int idx = blockIdx.x * 256 + threadIdx.x;
    if (idx < 105984) {                 // Wih[768][138] x-part -> WxT[128][768]
        int j = idx / 138, k = idx % 138;
        if (k < 128) WxT[k * 768 + j] = Wih[idx];
    }
    if (idx < 409600) {                 // W[co][ci][5][5] -> WT[tap][ci][co]
        int co = idx / 3200, r = idx % 3200;
        int ci = r / 25, tap = r % 25;
        int dst = (tap * 128 + ci) * 128 + co;
        W2T[dst] = W2[idx];
        W3T[dst] = W3[idx];
    }
    if (idx == 0) {                     // bool stored as int32? bytes 1,2,3 of each word all zero
        int nz = 0;
        for (int i = 0; i < 4096; i++) if ((i & 3) != 0) nz |= fmask[i];
        *flag = nz ? 0 : 1;
    }
}

// ---------------- conv1: [32,1,1024,40] -> X1[b][t][m1(8)][co(128)] ----------------
__global__ __launch_bounds__(256) void k_conv1(
    const float* __restrict__ X, const float* __restrict__ W1,
    const float* __restrict__ bb, const float* __restrict__ gg,
    const float* __restrict__ be, const float* __restrict__ mm_,
    const float* __restrict__ vv, float* __restrict__ X1)
{
    __shared__ __align__(16) float xs[8][44];
    __shared__ __align__(16) float ws[25][128];
    __shared__ float sc[128], sh[128];
    int bid = blockIdx.x;
    int b = bid >> 8, t0 = (bid & 255) << 2;
    int tid = threadIdx.x;
    for (int e = tid; e < 8 * 44; e += 256) {
        int tt = e / 44, mm = e % 44;
        int gt = t0 + tt - 2, gm = mm - 2;
        float val = 0.f;
        if (gt >= 0 && gt < 1024 && gm >= 0 && gm < 40)
            val = X[(b * 1024 + gt) * 40 + gm];
        xs[tt][mm] = val;
    }
    for (int e = tid; e < 3200; e += 256) {
        int tap = e >> 7, co = e & 127;
        ws[tap][co] = W1[co * 25 + tap];
    }
    if (tid < 128) {
        float s = gg[tid] / sqrtf(vv[tid] + EPSF);
        sc[tid] = s;
        sh[tid] = (bb[tid] - mm_[tid]) * s + be[tid];
    }
    __syncthreads();
    int cog = tid >> 5;          // 8 groups x 16 co
    int m1i = (tid >> 2) & 7;    // pooled mel
    int tp  = tid & 3;           // t'
    int co0 = cog * 16;
    float val[5][16];
#pragma unroll
    for (int p = 0; p < 5; p++)
#pragma unroll
        for (int i = 0; i < 16; i++) val[p][i] = 0.f;
#pragma unroll
    for (int dt = 0; dt < 5; dt++) {
#pragma unroll
        for (int dm = 0; dm < 5; dm++) {
            float w[16];
#pragma unroll
            for (int i = 0; i < 16; i += 4)
                *(float4*)&w[i] = *(const float4*)&ws[dt * 5 + dm][co0 + i];
#pragma unroll
            for (int p = 0; p < 5; p++) {
                float x = xs[tp + dt][m1i * 5 + p + dm];
#pragma unroll
                for (int i = 0; i < 16; i++) val[p][i] = fmaf(x, w[i], val[p][i]);
            }
        }
    }
    float outv[16];
#pragma unroll
    for (int i = 0; i < 16; i++) {
        float s = sc[co0 + i], h = sh[co0 + i];
        float mx = 0.f;
#pragma unroll
        for (int p = 0; p < 5; p++) {
            float y = fmaf(val[p][i], s, h);
            y = fmaxf(y, 0.f);
            mx = fmaxf(mx, y);
        }
        outv[i] = mx;
    }
    float* dst = &X1[(((long)(b * 1024 + t0 + tp)) * 8 + m1i) * 128 + co0];
#pragma unroll
    for (int i = 0; i < 16; i += 4) *(float4*)&dst[i] = *(float4*)&outv[i];
}

// ---------------- conv2: X1 -> X2[b][t][m2(2)][co(128)] ----------------
__global__ __launch_bounds__(256) void k_conv2(
    const float* __restrict__ X1, const float* __restrict__ W2T,
    const float* __restrict__ bb, const float* __restrict__ gg,
    const float* __restrict__ be, const float* __restrict__ mm_,
    const float* __restrict__ vv, float* __restrict__ X2)
{
    __shared__ __align__(16) float xs[20][33][12];  // [t''][ci(pad)][m']
    __shared__ __align__(16) float ws[5][32][64];   // [dm][ci][co]
    __shared__ float sc[64], sh[64];
    int bid = blockIdx.x;
    int coh = bid & 1, t0 = ((bid >> 1) & 63) << 4, b = bid >> 7;
    int co_base = coh * 64;
    int tid = threadIdx.x;
    int tp = tid & 15, cog = tid >> 4;   // 16 t' x 16 cog(4 co each)
    if (tid < 64) {
        int co = co_base + tid;
        float s = gg[co] / sqrtf(vv[co] + EPSF);
        sc[tid] = s;
        sh[tid] = (bb[co] - mm_[co]) * s + be[co];
    }
    float acc[4][8];
#pragma unroll
    for (int c = 0; c < 4; c++)
#pragma unroll
        for (int m = 0; m < 8; m++) acc[c][m] = 0.f;

    for (int cc = 0; cc < 4; cc++) {
        __syncthreads();
        for (int e = tid; e < 20 * 32 * 12; e += 256) {
            int ci = e & 31, mm = (e >> 5) % 12, tt = e / 384;
            int gt = t0 + tt - 2, gm = mm - 2;
            float v = 0.f;
            if (gt >= 0 && gt < 1024 && gm >= 0 && gm < 8)
                v = X1[(((long)(b * 1024 + gt)) * 8 + gm) * 128 + cc * 32 + ci];
            xs[tt][ci][mm] = v;
        }
        for (int dt = 0; dt < 5; dt++) {
            __syncthreads();
            for (int e = tid; e < 5 * 32 * 64; e += 256) {
                int co = e & 63, ci = (e >> 6) & 31, dm = e >> 11;
                ws[dm][ci][co] = W2T[((dt * 5 + dm) * 128 + cc * 32 + ci) * 128 + co_base + co];
            }
            __syncthreads();
            for (int ci = 0; ci < 32; ci++) {
                float x[12];
                *(float4*)&x[0] = *(const float4*)&xs[tp + dt][ci][0];
                *(float4*)&x[4] = *(const float4*)&xs[tp + dt][ci][4];
                *(float4*)&x[8] = *(const float4*)&xs[tp + dt][ci][8];
#pragma unroll
                for (int dm = 0; dm < 5; dm++) {
                    float w[4];
                    *(float4*)&w[0] = *(const float4*)&ws[dm][ci][cog * 4];
#pragma unroll
                    for (int c = 0; c < 4; c++)
#pragma unroll
                        for (int m = 0; m < 8; m++)
                            acc[c][m] = fmaf(w[c], x[m + dm], acc[c][m]);
                }
            }
        }
    }
    int t = t0 + tp;
#pragma unroll
    for (int m2 = 0; m2 < 2; m2++) {
        float4 ov;
        float* po = (float*)&ov;
#pragma unroll
        for (int c = 0; c < 4; c++) {
            float s = sc[cog * 4 + c], h = sh[cog * 4 + c];
            float mx = 0.f;
#pragma unroll
            for (int q = 0; q < 4; q++) {
                float y = fmaf(acc[c][m2 * 4 + q], s, h);
                y = fmaxf(y, 0.f);
                mx = fmaxf(mx, y);
            }
            po[c] = mx;
        }
        *(float4*)&X2[(((long)(b * 1024 + t)) * 2 + m2) * 128 + co_base + cog * 4] = ov;
    }
}

// ---------------- conv3: X2 -> F[t][b][co] (mel pooled to 1) ----------------
__global__ __launch_bounds__(256) void k_conv3(
    const float* __restrict__ X2, const float* __restrict__ W3T,
    const float* __restrict__ bb, const float* __restrict__ gg,
    const float* __restrict__ be, const float* __restrict__ mm_,
    const float* __restrict__ vv, float* __restrict__ F)
{
    __shared__ __align__(16) float xs[20][33][8];   // [t''][ci(pad)][m'] (m' 0..5 used)
    __shared__ __align__(16) float ws[5][32][64];
    __shared__ float sc[64], sh[64];
    int bid = blockIdx.x;
    int coh = bid & 1, t0 = ((bid >> 1) & 63) << 4, b = bid >> 7;
    int co_base = coh * 64;
    int tid = threadIdx.x;
    int tp = tid & 15, cog = tid >> 4;
    if (tid < 64) {
        int co = co_base + tid;
        float s = gg[co] / sqrtf(vv[co] + EPSF);
        sc[tid] = s;
        sh[tid] = (bb[co] - mm_[co]) * s + be[co];
    }
    float acc[4][2];
#pragma unroll
    for (int c = 0; c < 4; c++) { acc[c][0] = 0.f; acc[c][1] = 0.f; }

    for (int cc = 0; cc < 4; cc++) {
        __syncthreads();
        for (int e = tid; e < 20 * 32 * 8; e += 256) {
            int ci = e & 31, mm = (e >> 5) & 7, tt = e >> 8;
            int gt = t0 + tt - 2, gm = mm - 2;
            float v = 0.f;
            if (gt >= 0 && gt < 1024 && (gm == 0 || gm == 1))
                v = X2[(((long)(b * 1024 + gt)) * 2 + gm) * 128 + cc * 32 + ci];
            xs[tt][ci][mm] = v;
        }
        for (int dt = 0; dt < 5; dt++) {
            __syncthreads();
            for (int e = tid; e < 5 * 32 * 64; e += 256) {
                int co = e & 63, ci = (e >> 6) & 31, dm = e >> 11;
                ws[dm][ci][co] = W3T[((dt * 5 + dm) * 128 + cc * 32 + ci) * 128 + co_base + co];
            }
            __syncthreads();
            for (int ci = 0; ci < 32; ci++) {
                float x[8];
                *(float4*)&x[0] = *(const float4*)&xs[tp + dt][ci][0];
                *(float4*)&x[4] = *(const float4*)&xs[tp + dt][ci][4];
#pragma unroll
                for (int dm = 0; dm < 5; dm++) {
                    float w[4];
                    *(float4*)&w[0] = *(const float4*)&ws[dm][ci][cog * 4];
#pragma unroll
                    for (int c = 0; c < 4; c++) {
                        acc[c][0] = fmaf(w[c], x[0 + dm], acc[c][0]);
                        acc[c][1] = fmaf(w[c], x[1 + dm], acc[c][1]);
                    }
                }
            }
        }
    }
    float4 ov;
    float* po = (float*)&ov;
#pragma unroll
    for (int c = 0; c < 4; c++) {
        float s = sc[cog * 4 + c], h = sh[cog * 4 + c];
        float y0 = fmaxf(fmaf(acc[c][0], s, h), 0.f);
        float y1 = fmaxf(fmaf(acc[c][1], s, h), 0.f);
        po[c] = fmaxf(y0, y1);
    }
    *(float4*)&F[((long)(t0 + tp) * 32 + b) * 128 + co_base + cog * 4] = ov;
}

// ---------------- Gx = F @ Wihx.T + bih : [32768,128]x[128,768] ----------------
__global__ __launch_bounds__(256) void k_gemm(
    const float* __restrict__ F, const float* __restrict__ WxT,
    const float* __restrict__ bih, float* __restrict__ Gx)
{
    __shared__ __align__(16) float Fs[64][33];
    __shared__ __align__(16) float Ws[32][256];
    int bid = blockIdx.x;
    int jt = bid % 3, tb0 = (bid / 3) * 64;
    int tid = threadIdx.x;
    int tx = tid & 31, ty = tid >> 5;
    float acc[8][8];
#pragma unroll
    for (int i = 0; i < 8; i++)
#pragma unroll
        for (int j = 0; j < 8; j++) acc[i][j] = 0.f;
    for (int cc = 0; cc < 4; cc++) {
        __syncthreads();
        for (int e = tid; e < 64 * 32; e += 256) {
            int ci = e & 31, i = e >> 5;
            Fs[i][ci] = F[(long)(tb0 + i) * 128 + cc * 32 + ci];
        }
        for (int e = tid; e < 32 * 256; e += 256) {
            int jj = e & 255, ci = e >> 8;
            Ws[ci][jj] = WxT[(cc * 32 + ci) * 768 + jt * 256 + jj];
        }
        __syncthreads();
        for (int ci = 0; ci < 32; ci++) {
            float a[8], w[8];
#pragma unroll
            for (int i = 0; i < 8; i++) a[i] = Fs[ty * 8 + i][ci];
            *(float4*)&w[0] = *(const float4*)&Ws[ci][tx * 8];
            *(float4*)&w[4] = *(const float4*)&Ws[ci][tx * 8 + 4];
#pragma unroll
            for (int i = 0; i < 8; i++)
#pragma unroll
                for (int j = 0; j < 8; j++) acc[i][j] = fmaf(a[i], w[j], acc[i][j]);
        }
    }
    float bj[8];
#pragma unroll
    for (int j = 0; j < 8; j++) bj[j] = bih[jt * 256 + tx * 8 + j];
#pragma unroll
    for (int i = 0; i < 8; i++) {
        float o[8];
#pragma unroll
        for (int j = 0; j < 8; j++) o[j] = acc[i][j] + bj[j];
        float* dst = &Gx[(long)(tb0 + ty * 8 + i) * 768 + jt * 256 + tx * 8];
        *(float4*)&dst[0] = *(float4*)&o[0];
        *(float4*)&dst[4] = *(float4*)&o[4];
    }
}

// ===== sequential GRU: 1024 thr/batch, asm-pipelined Whh stream (16-deep vmcnt window) =====
// R5 counters (VGPR=56) proved the compiler rolls any C++ prefetch buffer into
// load->wait(0)->use (1 outstanding load). Here the 48 global_load_dwordx4 per
// thread per step are issued from inline asm through a 16-deep window with
// explicit s_waitcnt vmcnt(12/8/4/0) staging (hipBLASLt pattern; vmcnt waits on
// oldest-first). Compiler-issued loads (Gx/targets + prev out-store) are fenced
// ABOVE the window by a loop-top vmcnt(0)+memory fence; any still-pending extras
// only deepen the first wait (self-correcting). Arithmetic order identical to R5.
#define ISSUE4(A, B_, C, D, BASE, O0, O1, O2, O3)                      \
    asm volatile("global_load_dwordx4 %0, %4, off offset:" O0 "\n\t"   \
                 "global_load_dwordx4 %1, %4, off offset:" O1 "\n\t"   \
                 "global_load_dwordx4 %2, %4, off offset:" O2 "\n\t"   \
                 "global_load_dwordx4 %3, %4, off offset:" O3          \
                 : "=v"(A), "=v"(B_), "=v"(C), "=v"(D) : "v"(BASE))

#define WAIT4(N, A, B_, C, D)                                          \
    asm volatile("s_waitcnt vmcnt(" N ")"                              \
                 : "=v"(A), "=v"(B_), "=v"(C), "=v"(D)                 \
                 : "0"(A), "1"(B_), "2"(C), "3"(D))

#define ROWDOT(A, B_, C, D, IDX) do {                                            \
    float s_ = 0.f;                                                              \
    s_ = fmaf(A.x, hv0.x, s_); s_ = fmaf(A.y, hv0.y, s_);                        \
    s_ = fmaf(A.z, hv0.z, s_); s_ = fmaf(A.w, hv0.w, s_);                        \
    s_ = fmaf(B_.x, hv1.x, s_); s_ = fmaf(B_.y, hv1.y, s_);                      \
    s_ = fmaf(B_.z, hv1.z, s_); s_ = fmaf(B_.w, hv1.w, s_);                      \
    s_ = fmaf(C.x, hv2.x, s_); s_ = fmaf(C.y, hv2.y, s_);                        \
    s_ = fmaf(C.z, hv2.z, s_); s_ = fmaf(C.w, hv2.w, s_);                        \
    s_ = fmaf(D.x, hv3.x, s_); s_ = fmaf(D.y, hv3.y, s_);                        \
    s_ = fmaf(D.z, hv3.z, s_); s_ = fmaf(D.w, hv3.w, s_);                        \
    s_ = dpp_add<0x111>(s_); s_ = dpp_add<0x112>(s_);                            \
    s_ = dpp_add<0x114>(s_); s_ = dpp_add<0x118>(s_);                            \
    if (kgs == 15) gsum[rg * 12 + (IDX)] = s_;                                   \
} while (0)

__global__ __attribute__((amdgpu_waves_per_eu(4, 4))) __launch_bounds__(1024) void k_gru(
    const float* __restrict__ Whh, const float* __restrict__ Gx,
    const float* __restrict__ Wih, const float* __restrict__ bhh_g,
    const float* __restrict__ Wf, const float* __restrict__ bf_g,
    const float* __restrict__ targets, const unsigned char* __restrict__ fmask,
    const int* __restrict__ flag, float* __restrict__ out)
{
    __shared__ __align__(16) float hq[8 * 268];   // 8 copies of h[256], stride 268
    __shared__ float gsum[768];
    __shared__ float tfl[16];
    __shared__ float wtfL[30 * 256];              // [g*10+c][j]
    __shared__ float WfL[2560];                   // [oc][256]
    const int b = blockIdx.x, tid = threadIdx.x;
    const int kgs = tid & 15, rg = tid >> 4;      // rows rg*12..+12, cols kgs*16..+16

    const bool isGate = (tid < 256);
    float bh0 = 0.f, bh1 = 0.f, bh2 = 0.f, hold = 0.f;
    if (isGate) { bh0 = bhh_g[tid]; bh1 = bhh_g[tid + 256]; bh2 = bhh_g[tid + 512]; }
    const bool isProj = (tid >= 256 && tid < 416);
    const int oc = (tid - 256) >> 4, seg = tid & 15;
    float bfc = isProj ? bf_g[oc] : 0.f;
    const bool isWr = isProj && (seg == 15);
    const int int32mode = flag[0];

    for (int e = tid; e < 7680; e += 1024) {      // tf-projection weights -> LDS
        int cp = e >> 8, jj = e & 255;
        int g = cp / 10, c = cp - g * 10;
        wtfL[e] = Wih[(g * 256 + jj) * 138 + 128 + c];
    }
    for (int e = tid; e < 2560; e += 1024) WfL[e] = Wf[e];
    for (int e = tid; e < 8 * 268; e += 1024) hq[e] = 0.f;
    if (tid < 16) tfl[tid] = 0.f;
    __syncthreads();

    const f4* hbase = (const f4*)&hq[(kgs >> 1) * 268 + kgs * 16];
    const float* b0 = Whh + rg * 12 * 256 + kgs * 16;   // rows 0-3 of this thread
    const float* b1 = b0 + 4 * 256;                     // rows 4-7
    const float* b2 = b0 + 8 * 256;                     // rows 8-11

    for (int t = 0; t < 1024; t++) {
        // drain prev-iteration out-store (and anything else) so vmcnt counting is clean
        asm volatile("s_waitcnt vmcnt(0)" ::: "memory");

        // compiler-visible prefetches (stay ABOVE the asm window via the fence below)
        float gxr = 0.f, gxz = 0.f, gxn = 0.f;
        if (isGate) {
            const float* gx = &Gx[((long)t * 32 + b) * 768];
            gxr = gx[tid]; gxz = gx[tid + 256]; gxn = gx[tid + 512];
        }
        float tgt = 0.f; int fmv = 0;
        if (isWr) {
            tgt = targets[((long)b * 1024 + t) * 10 + oc];
            fmv = int32mode ? ((const int*)fmask)[t * 32 + b] : (int)fmask[t * 32 + b];
        }
        f4 hv0 = hbase[0], hv1 = hbase[1], hv2 = hbase[2], hv3 = hbase[3];
        asm volatile("" ::: "memory");   // fence: no compiler mem ops inside the window

        f4 s0a, s0b, s0c, s0d, s1a, s1b, s1c, s1d;
        f4 s2a, s2b, s2c, s2d, s3a, s3b, s3c, s3d;

        // fill window: rows 0-3 (16 loads in flight)
        ISSUE4(s0a, s0b, s0c, s0d, b0, "0", "16", "32", "48");
        ISSUE4(s1a, s1b, s1c, s1d, b0, "1024", "1040", "1056", "1072");
        ISSUE4(s2a, s2b, s2c, s2d, b0, "2048", "2064", "2080", "2096");
        ISSUE4(s3a, s3b, s3c, s3d, b0, "3072", "3088", "3104", "3120");
        // steady state: wait oldest row, consume, reissue
        WAIT4("12", s0a, s0b, s0c, s0d); ROWDOT(s0a, s0b, s0c, s0d, 0);
        ISSUE4(s0a, s0b, s0c, s0d, b1, "0", "16", "32", "48");
        WAIT4("12", s1a, s1b, s1c, s1d); ROWDOT(s1a, s1b, s1c, s1d, 1);
        ISSUE4(s1a, s1b, s1c, s1d, b1, "1024", "1040", "1056", "1072");
        WAIT4("12", s2a, s2b, s2c, s2d); ROWDOT(s2a, s2b, s2c, s2d, 2);
        ISSUE4(s2a, s2b, s2c, s2d, b1, "2048", "2064", "2080", "2096");
        WAIT4("12", s3a, s3b, s3c, s3d); ROWDOT(s3a, s3b, s3c, s3d, 3);
        ISSUE4(s3a, s3b, s3c, s3d, b1, "3072", "3088", "3104", "3120");
        WAIT4("12", s0a, s0b, s0c, s0d); ROWDOT(s0a, s0b, s0c, s0d, 4);
        ISSUE4(s0a, s0b, s0c, s0d, b2, "0", "16", "32", "48");
        WAIT4("12", s1a, s1b, s1c, s1d); ROWDOT(s1a, s1b, s1c, s1d, 5);
        ISSUE4(s1a, s1b, s1c, s1d, b2, "1024", "1040", "1056", "1072");
        WAIT4("12", s2a, s2b, s2c, s2d); ROWDOT(s2a, s2b, s2c, s2d, 6);
        ISSUE4(s2a, s2b, s2c, s2d, b2, "2048", "2064", "2080", "2096");
        WAIT4("12", s3a, s3b, s3c, s3d); ROWDOT(s3a, s3b, s3c, s3d, 7);
        ISSUE4(s3a, s3b, s3c, s3d, b2, "3072", "3088", "3104", "3120");
        // tail: drain window
        WAIT4("12", s0a, s0b, s0c, s0d); ROWDOT(s0a, s0b, s0c, s0d, 8);
        WAIT4("8",  s1a, s1b, s1c, s1d); ROWDOT(s1a, s1b, s1c, s1d, 9);
        WAIT4("4",  s2a, s2b, s2c, s2d); ROWDOT(s2a, s2b, s2c, s2d, 10);
        WAIT4("0",  s3a, s3b, s3c, s3d); ROWDOT(s3a, s3b, s3c, s3d, 11);

        __syncthreads();  // B1: gsum ready

        // ---- gate stage (threads 0..255): j = tid ----
        if (isGate) {
            float gr = gxr, gz = gxz, gn = gxn;
#pragma unroll
            for (int c = 0; c < 10; c++) {
                float tv = tfl[c];
                gr = fmaf(tv, wtfL[c * 256 + tid], gr);
                gz = fmaf(tv, wtfL[(10 + c) * 256 + tid], gz);
                gn = fmaf(tv, wtfL[(20 + c) * 256 + tid], gn);
            }
            float ar = gsum[tid] + bh0;
            float az = gsum[tid + 256] + bh1;
            float an = gsum[tid + 512] + bh2;
            float r = 1.0f / (1.0f + expf(-(gr + ar)));
            float z = 1.0f / (1.0f + expf(-(gz + az)));
            float n = tanhf(fmaf(r, an, gn));
            float hnew = (1.0f - z) * n + z * hold;
            hold = hnew;
#pragma unroll
            for (int c = 0; c < 8; c++) hq[c * 268 + tid] = hnew;
        }
        __syncthreads();  // B2: h ready

        // ---- out projection (threads 256..415) + tf update ----
        if (isProj) {
            const float* hp = &hq[(seg >> 1) * 268 + seg * 16];
            const float* wfp = &WfL[oc * 256 + seg * 16];
            float s = 0.f;
#pragma unroll
            for (int i = 0; i < 16; i++) s = fmaf(wfp[i], hp[i], s);
            s = dpp_add<0x111>(s);
            s = dpp_add<0x112>(s);
            s = dpp_add<0x114>(s);
            s = dpp_add<0x118>(s);   // lane seg==15 holds full sum
            if (isWr) {
                float o = s + bfc;
                out[((long)b * 1024 + t) * 10 + oc] = o;
                float pred = (o > 0.f) ? 1.f : 0.f;
                tfl[oc] = fmv ? tgt : pred;
            }
        }
        // no 3rd barrier: hq consumed next step only after writers passed B2;
        // gsum/tfl hazards separated by B1/B2.
    }
}

extern "C" void kernel_launch(void* const* d_in, const int* in_sizes, int n_in,
                              void* d_out, int out_size, void* d_ws, size_t ws_size,
                              hipStream_t stream) {
    (void)in_sizes; (void)n_in; (void)out_size; (void)ws_size;
    const float* features = (const float*)d_in[0];
    const float* targets  = (const float*)d_in[1];
    const unsigned char* fmask = (const unsigned char*)d_in[2];
    const float* W1  = (const float*)d_in[3];
    const float* b1  = (const float*)d_in[4];
    const float* g1  = (const float*)d_in[5];
    const float* be1 = (const float*)d_in[6];
    const float* m1  = (const float*)d_in[7];
    const float* v1  = (const float*)d_in[8];
    const float* W2  = (const float*)d_in[9];
    const float* b2  = (const float*)d_in[10];
    const float* g2  = (const float*)d_in[11];
    const float* be2 = (const float*)d_in[12];
    const float* m2  = (const float*)d_in[13];
    const float* v2  = (const float*)d_in[14];
    const float* W3  = (const float*)d_in[15];
    const float* b3  = (const float*)d_in[16];
    const float* g3  = (const float*)d_in[17];
    const float* be3 = (const float*)d_in[18];
    const float* m3  = (const float*)d_in[19];
    const float* v3  = (const float*)d_in[20];
    const float* Wih = (const float*)d_in[21];
    const float* Whh = (const float*)d_in[22];
    const float* bih = (const float*)d_in[23];
    const float* bhh = (const float*)d_in[24];
    const float* Wf  = (const float*)d_in[25];
    const float* bf  = (const float*)d_in[26];

    char* w = (char*)d_ws;
    float* WxT = (float*)(w + 786432);                  // 393216 B
    float* W2T = (float*)(w + 1179648);                 // 1638400 B
    float* W3T = (float*)(w + 2818048);                 // 1638400 B
    int*   flag = (int*)(w + 4456448);                  // 512 B slot
    float* X1  = (float*)(w + 4456960);                 // 128 MB; reused as Gx after conv2
    float* Gx  = X1;
    float* X2  = (float*)(w + 4456960 + 134217728);     // 32 MB
    float* F   = (float*)(w + 4456960 + 134217728 + 33554432); // 16 MB
    float* out = (float*)d_out;

    k_prep<<<1600, 256, 0, stream>>>(Wih, W2, W3, fmask, WxT, W2T, W3T, flag);
    k_conv1<<<8192, 256, 0, stream>>>(features, W1, b1, g1, be1, m1, v1, X1);
    k_conv2<<<4096, 256, 0, stream>>>(X1, W2T, b2, g2, be2, m2, v2, X2);
    k_conv3<<<4096, 256, 0, stream>>>(X2, W3T, b3, g3, be3, m3, v3, F);
    k_gemm<<<1536, 256, 0, stream>>>(F, WxT, bih, Gx);
    k_gru<<<32, 1024, 0, stream>>>(Whh, Gx, Wih, bhh, Wf, bf, targets, fmask, flag, out);
}

// Round 8
// 14616.948 us; speedup vs baseline: 1.5364x; 1.2148x over previous
//
#include <hip/hip_runtime.h>
#include <math.h>

#define EPSF 1e-5f

typedef __attribute__((ext_vector_type(4))) float f4;

// DPP helper: v += value from lane (i - N) within the 16-lane DPP row (0 if OOB)
template<int CTRL>
__device__ __forceinline__ float dpp_add(float v) {
    int s = __builtin_amdgcn_update_dpp(0, __float_as_int(v), CTRL, 0xf, 0xf, true);
    return v + __int_as_float(s);
}

// async global->LDS, 16B per lane; LDS dest = uniform base + lane*16 (m97/m104)
__device__ __forceinline__ void gl_lds16(const float* g, float* l) {
    __builtin_amdgcn_global_load_lds(
        (const __attribute__((address_space(1))) void*)g,
        (__attribute__((address_space(3))) void*)l, 16, 0, 0);
}

// ---------------- prep: weight transposes + bool-dtype detect ----------------
__global__ __launch_bounds__(256) void k_prep(
    const float* __restrict__ Wih, const float* __restrict__ Whh,
    const float* __restrict__ W2, const float* __restrict__ W3,
    const unsigned char* __restrict__ fmask,
    float* __restrict__ WhhTs, float* __restrict__ WxT,
    float* __restrict__ W2T, float* __restrict__ W3T, int* __restrict__ flag)
{
    int idx = blockIdx.x * 256 + threadIdx.x;
    if (idx < 196608) {                 // Whh[768][256] -> WhhTs[k/4][j][4] (k-interleaved T)
        int j = idx >> 8, k = idx & 255;
        WhhTs[((k >> 2) * 768 + j) * 4 + (k & 3)] = Whh[idx];
    }
    if (idx < 105984) {                 // Wih[768][138] x-part -> WxT[128][768]
        int j = idx / 138, k = idx % 138;
        if (k < 128) WxT[k * 768 + j] = Wih[idx];
    }
    if (idx < 409600) {                 // W[co][ci][5][5] -> WT[tap][ci][co]
        int co = idx / 3200, r = idx % 3200;
        int ci = r / 25, tap = r % 25;
        int dst = (tap * 128 + ci) * 128 + co;
        W2T[dst] = W2[idx];
        W3T[dst] = W3[idx];
    }
    if (idx == 0) {                     // bool stored as int32? bytes 1,2,3 of each word all zero
        int nz = 0;
        for (int i = 0; i < 4096; i++) if ((i & 3) != 0) nz |= fmask[i];
        *flag = nz ? 0 : 1;
    }
}

// ---------------- conv1: [32,1,1024,40] -> X1[b][t][m1(8)][co(128)] ----------------
__global__ __launch_bounds__(256) void k_conv1(
    const float* __restrict__ X, const float* __restrict__ W1,
    const float* __restrict__ bb, const float* __restrict__ gg,
    const float* __restrict__ be, const float* __restrict__ mm_,
    const float* __restrict__ vv, float* __restrict__ X1)
{
    __shared__ __align__(16) float xs[8][44];
    __shared__ __align__(16) float ws[25][128];
    __shared__ float sc[128], sh[128];
    int bid = blockIdx.x;
    int b = bid >> 8, t0 = (bid & 255) << 2;
    int tid = threadIdx.x;
    for (int e = tid; e < 8 * 44; e += 256) {
        int tt = e / 44, mm = e % 44;
        int gt = t0 + tt - 2, gm = mm - 2;
        float val = 0.f;
        if (gt >= 0 && gt < 1024 && gm >= 0 && gm < 40)
            val = X[(b * 1024 + gt) * 40 + gm];
        xs[tt][mm] = val;
    }
    for (int e = tid; e < 3200; e += 256) {
        int tap = e >> 7, co = e & 127;
        ws[tap][co] = W1[co * 25 + tap];
    }
    if (tid < 128) {
        float s = gg[tid] / sqrtf(vv[tid] + EPSF);
        sc[tid] = s;
        sh[tid] = (bb[tid] - mm_[tid]) * s + be[tid];
    }
    __syncthreads();
    int cog = tid >> 5;          // 8 groups x 16 co
    int m1i = (tid >> 2) & 7;    // pooled mel
    int tp  = tid & 3;           // t'
    int co0 = cog * 16;
    float val[5][16];
#pragma unroll
    for (int p = 0; p < 5; p++)
#pragma unroll
        for (int i = 0; i < 16; i++) val[p][i] = 0.f;
#pragma unroll
    for (int dt = 0; dt < 5; dt++) {
#pragma unroll
        for (int dm = 0; dm < 5; dm++) {
            float w[16];
#pragma unroll
            for (int i = 0; i < 16; i += 4)
                *(float4*)&w[i] = *(const float4*)&ws[dt * 5 + dm][co0 + i];
#pragma unroll
            for (int p = 0; p < 5; p++) {
                float x = xs[tp + dt][m1i * 5 + p + dm];
#pragma unroll
                for (int i = 0; i < 16; i++) val[p][i] = fmaf(x, w[i], val[p][i]);
            }
        }
    }
    float outv[16];
#pragma unroll
    for (int i = 0; i < 16; i++) {
        float s = sc[co0 + i], h = sh[co0 + i];
        float mx = 0.f;
#pragma unroll
        for (int p = 0; p < 5; p++) {
            float y = fmaf(val[p][i], s, h);
            y = fmaxf(y, 0.f);
            mx = fmaxf(mx, y);
        }
        outv[i] = mx;
    }
    float* dst = &X1[(((long)(b * 1024 + t0 + tp)) * 8 + m1i) * 128 + co0];
#pragma unroll
    for (int i = 0; i < 16; i += 4) *(float4*)&dst[i] = *(float4*)&outv[i];
}

// ---------------- conv2: X1 -> X2[b][t][m2(2)][co(128)] ----------------
__global__ __launch_bounds__(256) void k_conv2(
    const float* __restrict__ X1, const float* __restrict__ W2T,
    const float* __restrict__ bb, const float* __restrict__ gg,
    const float* __restrict__ be, const float* __restrict__ mm_,
    const float* __restrict__ vv, float* __restrict__ X2)
{
    __shared__ __align__(16) float xs[20][33][12];  // [t''][ci(pad)][m']
    __shared__ __align__(16) float ws[5][32][64];   // [dm][ci][co]
    __shared__ float sc[64], sh[64];
    int bid = blockIdx.x;
    int coh = bid & 1, t0 = ((bid >> 1) & 63) << 4, b = bid >> 7;
    int co_base = coh * 64;
    int tid = threadIdx.x;
    int tp = tid & 15, cog = tid >> 4;   // 16 t' x 16 cog(4 co each)
    if (tid < 64) {
        int co = co_base + tid;
        float s = gg[co] / sqrtf(vv[co] + EPSF);
        sc[tid] = s;
        sh[tid] = (bb[co] - mm_[co]) * s + be[co];
    }
    float acc[4][8];
#pragma unroll
    for (int c = 0; c < 4; c++)
#pragma unroll
        for (int m = 0; m < 8; m++) acc[c][m] = 0.f;

    for (int cc = 0; cc < 4; cc++) {
        __syncthreads();
        for (int e = tid; e < 20 * 32 * 12; e += 256) {
            int ci = e & 31, mm = (e >> 5) % 12, tt = e / 384;
            int gt = t0 + tt - 2, gm = mm - 2;
            float v = 0.f;
            if (gt >= 0 && gt < 1024 && gm >= 0 && gm < 8)
                v = X1[(((long)(b * 1024 + gt)) * 8 + gm) * 128 + cc * 32 + ci];
            xs[tt][ci][mm] = v;
        }
        for (int dt = 0; dt < 5; dt++) {
            __syncthreads();
            for (int e = tid; e < 5 * 32 * 64; e += 256) {
                int co = e & 63, ci = (e >> 6) & 31, dm = e >> 11;
                ws[dm][ci][co] = W2T[((dt * 5 + dm) * 128 + cc * 32 + ci) * 128 + co_base + co];
            }
            __syncthreads();
            for (int ci = 0; ci < 32; ci++) {
                float x[12];
                *(float4*)&x[0] = *(const float4*)&xs[tp + dt][ci][0];
                *(float4*)&x[4] = *(const float4*)&xs[tp + dt][ci][4];
                *(float4*)&x[8] = *(const float4*)&xs[tp + dt][ci][8];
#pragma unroll
                for (int dm = 0; dm < 5; dm++) {
                    float w[4];
                    *(float4*)&w[0] = *(const float4*)&ws[dm][ci][cog * 4];
#pragma unroll
                    for (int c = 0; c < 4; c++)
#pragma unroll
                        for (int m = 0; m < 8; m++)
                            acc[c][m] = fmaf(w[c], x[m + dm], acc[c][m]);
                }
            }
        }
    }
    int t = t0 + tp;
#pragma unroll
    for (int m2 = 0; m2 < 2; m2++) {
        float4 ov;
        float* po = (float*)&ov;
#pragma unroll
        for (int c = 0; c < 4; c++) {
            float s = sc[cog * 4 + c], h = sh[cog * 4 + c];
            float mx = 0.f;
#pragma unroll
            for (int q = 0; q < 4; q++) {
                float y = fmaf(acc[c][m2 * 4 + q], s, h);
                y = fmaxf(y, 0.f);
                mx = fmaxf(mx, y);
            }
            po[c] = mx;
        }
        *(float4*)&X2[(((long)(b * 1024 + t)) * 2 + m2) * 128 + co_base + cog * 4] = ov;
    }
}

// ---------------- conv3: X2 -> F[t][b][co] (mel pooled to 1) ----------------
__global__ __launch_bounds__(256) void k_conv3(
    const float* __restrict__ X2, const float* __restrict__ W3T,
    const float* __restrict__ bb, const float* __restrict__ gg,
    const float* __restrict__ be, const float* __restrict__ mm_,
    const float* __restrict__ vv, float* __restrict__ F)
{
    __shared__ __align__(16) float xs[20][33][8];   // [t''][ci(pad)][m'] (m' 0..5 used)
    __shared__ __align__(16) float ws[5][32][64];
    __shared__ float sc[64], sh[64];
    int bid = blockIdx.x;
    int coh = bid & 1, t0 = ((bid >> 1) & 63) << 4, b = bid >> 7;
    int co_base = coh * 64;
    int tid = threadIdx.x;
    int tp = tid & 15, cog = tid >> 4;
    if (tid < 64) {
        int co = co_base + tid;
        float s = gg[co] / sqrtf(vv[co] + EPSF);
        sc[tid] = s;
        sh[tid] = (bb[co] - mm_[co]) * s + be[co];
    }
    float acc[4][2];
#pragma unroll
    for (int c = 0; c < 4; c++) { acc[c][0] = 0.f; acc[c][1] = 0.f; }

    for (int cc = 0; cc < 4; cc++) {
        __syncthreads();
        for (int e = tid; e < 20 * 32 * 8; e += 256) {
            int ci = e & 31, mm = (e >> 5) & 7, tt = e >> 8;
            int gt = t0 + tt - 2, gm = mm - 2;
            float v = 0.f;
            if (gt >= 0 && gt < 1024 && (gm == 0 || gm == 1))
                v = X2[(((long)(b * 1024 + gt)) * 2 + gm) * 128 + cc * 32 + ci];
            xs[tt][ci][mm] = v;
        }
        for (int dt = 0; dt < 5; dt++) {
            __syncthreads();
            for (int e = tid; e < 5 * 32 * 64; e += 256) {
                int co = e & 63, ci = (e >> 6) & 31, dm = e >> 11;
                ws[dm][ci][co] = W3T[((dt * 5 + dm) * 128 + cc * 32 + ci) * 128 + co_base + co];
            }
            __syncthreads();
            for (int ci = 0; ci < 32; ci++) {
                float x[8];
                *(float4*)&x[0] = *(const float4*)&xs[tp + dt][ci][0];
                *(float4*)&x[4] = *(const float4*)&xs[tp + dt][ci][4];
#pragma unroll
                for (int dm = 0; dm < 5; dm++) {
                    float w[4];
                    *(float4*)&w[0] = *(const float4*)&ws[dm][ci][cog * 4];
#pragma unroll
                    for (int c = 0; c < 4; c++) {
                        acc[c][0] = fmaf(w[c], x[0 + dm], acc[c][0]);
                        acc[c][1] = fmaf(w[c], x[1 + dm], acc[c][1]);
                    }
                }
            }
        }
    }
    float4 ov;
    float* po = (float*)&ov;
#pragma unroll
    for (int c = 0; c < 4; c++) {
        float s = sc[cog * 4 + c], h = sh[cog * 4 + c];
        float y0 = fmaxf(fmaf(acc[c][0], s, h), 0.f);
        float y1 = fmaxf(fmaf(acc[c][1], s, h), 0.f);
        po[c] = fmaxf(y0, y1);
    }
    *(float4*)&F[((long)(t0 + tp) * 32 + b) * 128 + co_base + cog * 4] = ov;
}

// ---------------- Gx = F @ Wihx.T + bih : [32768,128]x[128,768] ----------------
__global__ __launch_bounds__(256) void k_gemm(
    const float* __restrict__ F, const float* __restrict__ WxT,
    const float* __restrict__ bih, float* __restrict__ Gx)
{
    __shared__ __align__(16) float Fs[64][33];
    __shared__ __align__(16) float Ws[32][256];
    int bid = blockIdx.x;
    int jt = bid % 3, tb0 = (bid / 3) * 64;
    int tid = threadIdx.x;
    int tx = tid & 31, ty = tid >> 5;
    float acc[8][8];
#pragma unroll
    for (int i = 0; i < 8; i++)
#pragma unroll
        for (int j = 0; j < 8; j++) acc[i][j] = 0.f;
    for (int cc = 0; cc < 4; cc++) {
        __syncthreads();
        for (int e = tid; e < 64 * 32; e += 256) {
            int ci = e & 31, i = e >> 5;
            Fs[i][ci] = F[(long)(tb0 + i) * 128 + cc * 32 + ci];
        }
        for (int e = tid; e < 32 * 256; e += 256) {
            int jj = e & 255, ci = e >> 8;
            Ws[ci][jj] = WxT[(cc * 32 + ci) * 768 + jt * 256 + jj];
        }
        __syncthreads();
        for (int ci = 0; ci < 32; ci++) {
            float a[8], w[8];
#pragma unroll
            for (int i = 0; i < 8; i++) a[i] = Fs[ty * 8 + i][ci];
            *(float4*)&w[0] = *(const float4*)&Ws[ci][tx * 8];
            *(float4*)&w[4] = *(const float4*)&Ws[ci][tx * 8 + 4];
#pragma unroll
            for (int i = 0; i < 8; i++)
#pragma unroll
                for (int j = 0; j < 8; j++) acc[i][j] = fmaf(a[i], w[j], acc[i][j]);
        }
    }
    float bj[8];
#pragma unroll
    for (int j = 0; j < 8; j++) bj[j] = bih[jt * 256 + tx * 8 + j];
#pragma unroll
    for (int i = 0; i < 8; i++) {
        float o[8];
#pragma unroll
        for (int j = 0; j < 8; j++) o[j] = acc[i][j] + bj[j];
        float* dst = &Gx[(long)(tb0 + ty * 8 + i) * 768 + jt * 256 + tx * 8];
        *(float4*)&dst[0] = *(float4*)&o[0];
        *(float4*)&dst[4] = *(float4*)&o[4];
    }
}

// ====== GRU: producer/consumer global_load_lds ring, 1024 thr/batch ======
// Waves 12-15 (producers) continuously stage WhhTs in 8-k chunks (24KB, 24
// gl_lds16 instrs) into a 6-slot LDS ring, throttled with s_waitcnt vmcnt(24)
// (5 chunks in flight). Waves 0-11 (consumers): thread j in [0,768) owns the
// FULL dot gsum_j; per chunk 2 coalesced b128 buf reads + 2 broadcast b128 h
// reads + 8 FMAs. Raw s_barrier (not __syncthreads) so the compiler never
// drains the producers' vmcnt queue (the m97 barrier-drain trap). DS pipe is
// FIFO per CU, so LDS writes before a raw barrier are seen by readers after it.
__global__ __attribute__((amdgpu_waves_per_eu(4, 4))) __launch_bounds__(1024) void k_gru(
    const float* __restrict__ WhhTs, const float* __restrict__ Gx,
    const float* __restrict__ Wih, const float* __restrict__ bhh_g,
    const float* __restrict__ Wf, const float* __restrict__ bf_g,
    const float* __restrict__ targets, const unsigned char* __restrict__ fmask,
    const int* __restrict__ flag, float* __restrict__ out)
{
    extern __shared__ float lds[];
    float* buf  = lds;              // 6 slots * 6144 floats = 147456 B
    float* hq   = lds + 36864;      // 256
    float* gsum = hq + 256;         // 768
    float* tfl  = gsum + 768;       // 16
    const int b = blockIdx.x, tid = threadIdx.x;
    const bool isCons = (tid < 768);
    const bool isGate = (tid < 256);
    const bool isProj = (tid >= 256 && tid < 416);
    const bool isProd = (tid >= 768);

    float wtf0[10], wtf1[10], wtf2[10];
    float bh0 = 0.f, bh1 = 0.f, bh2 = 0.f, hold = 0.f;
    if (isGate) {
#pragma unroll
        for (int c = 0; c < 10; c++) {
            wtf0[c] = Wih[tid * 138 + 128 + c];
            wtf1[c] = Wih[(tid + 256) * 138 + 128 + c];
            wtf2[c] = Wih[(tid + 512) * 138 + 128 + c];
        }
        bh0 = bhh_g[tid]; bh1 = bhh_g[tid + 256]; bh2 = bhh_g[tid + 512];
    }
    const int oc = (tid - 256) >> 4, seg = tid & 15;
    float wf16[16];
    float bfc = 0.f;
    int int32mode = 0;
    if (isProj) {
#pragma unroll
        for (int i = 0; i < 16; i++) wf16[i] = Wf[oc * 256 + seg * 16 + i];
        bfc = bf_g[oc];
        int32mode = flag[0];
    }
    const bool isWr = isProj && (seg == 15);

    if (tid < 256) hq[tid] = 0.f;
    if (tid < 16) tfl[tid] = 0.f;
    __syncthreads();   // before any gl_lds is outstanding: safe

    // producer constants: wave wv in [0,4), instrs i = wv*6+i6; K=i/12, p=i%12
    const int lane = tid & 63;
    const int wv = (tid >> 6) - 12;
    int ioff[6];
#pragma unroll
    for (int i6 = 0; i6 < 6; i6++) {
        int i = wv * 6 + i6;
        ioff[i6] = (i / 12) * 3072 + (i % 12) * 256;
    }
    // prologue: stage chunks 0..4
    if (isProd) {
        for (int g = 0; g < 5; g++) {
            const float* srcb = WhhTs + g * 6144;
            float* dstb = buf + g * 6144;
#pragma unroll
            for (int i6 = 0; i6 < 6; i6++)
                gl_lds16(srcb + ioff[i6] + lane * 4, dstb + ioff[i6]);
        }
        asm volatile("s_waitcnt vmcnt(24)");   // chunk 0 arrived
    }
    asm volatile("s_barrier" ::: "memory");

    const f4* fb = (const f4*)buf;
    const f4* fh = (const f4*)hq;
    int slotc = 0, slotp = 5;

    for (int t = 0; t < 1024; t++) {
        float gxr = 0.f, gxz = 0.f, gxn = 0.f;
        if (isGate) {
            const float* gx = &Gx[((long)t * 32 + b) * 768];
            gxr = gx[tid]; gxz = gx[tid + 256]; gxn = gx[tid + 512];
        }
        float tgt = 0.f; int fmv = 0;
        if (isWr) {
            tgt = targets[((long)b * 1024 + t) * 10 + oc];
            fmv = int32mode ? ((const int*)fmask)[t * 32 + b] : (int)fmask[t * 32 + b];
        }
        float acc = 0.f;

        for (int c = 0; c < 32; c++) {
            if (isProd) {
                int cp = c + 5; if (cp >= 32) cp -= 32;       // chunk-in-step being staged
                const float* srcb = WhhTs + cp * 6144;
                float* dstb = buf + slotp * 6144;
#pragma unroll
                for (int i6 = 0; i6 < 6; i6++)
                    gl_lds16(srcb + ioff[i6] + lane * 4, dstb + ioff[i6]);
                asm volatile("s_waitcnt vmcnt(24)");           // chunk c+1 arrived
            } else if (isCons) {
                f4 w0 = fb[slotc * 1536 + tid];
                f4 w1 = fb[slotc * 1536 + 768 + tid];
                f4 h0 = fh[2 * c], h1 = fh[2 * c + 1];
                acc = fmaf(w0.x, h0.x, acc); acc = fmaf(w0.y, h0.y, acc);
                acc = fmaf(w0.z, h0.z, acc); acc = fmaf(w0.w, h0.w, acc);
                acc = fmaf(w1.x, h1.x, acc); acc = fmaf(w1.y, h1.y, acc);
                acc = fmaf(w1.z, h1.z, acc); acc = fmaf(w1.w, h1.w, acc);
            }
            slotc++; if (slotc == 6) slotc = 0;
            slotp++; if (slotp == 6) slotp = 0;
            asm volatile("s_barrier" ::: "memory");
        }

        if (isCons) gsum[tid] = acc;
        asm volatile("s_barrier" ::: "memory");   // B1: gsum ready

        if (isGate) {
            float gr = gxr, gz = gxz, gn = gxn;
#pragma unroll
            for (int c = 0; c < 10; c++) {
                float tv = tfl[c];
                gr = fmaf(tv, wtf0[c], gr);
                gz = fmaf(tv, wtf1[c], gz);
                gn = fmaf(tv, wtf2[c], gn);
            }
            float ar = gsum[tid] + bh0;
            float az = gsum[tid + 256] + bh1;
            float an = gsum[tid + 512] + bh2;
            float r = 1.0f / (1.0f + expf(-(gr + ar)));
            float z = 1.0f / (1.0f + expf(-(gz + az)));
            float n = tanhf(fmaf(r, an, gn));
            float hnew = (1.0f - z) * n + z * hold;
            hold = hnew;
            hq[tid] = hnew;
        }
        asm volatile("s_barrier" ::: "memory");   // B2: h ready

        if (isProj) {
            const float* hp = &hq[seg * 16];
            float s = 0.f;
#pragma unroll
            for (int i = 0; i < 16; i++) s = fmaf(wf16[i], hp[i], s);
            s = dpp_add<0x111>(s);
            s = dpp_add<0x112>(s);
            s = dpp_add<0x114>(s);
            s = dpp_add<0x118>(s);   // lane seg==15 holds full sum
            if (isWr) {
                float o = s + bfc;
                out[((long)b * 1024 + t) * 10 + oc] = o;
                float pred = (o > 0.f) ? 1.f : 0.f;
                tfl[oc] = fmv ? tgt : pred;
            }
        }
        // no extra barrier: tfl/hq consumers are separated by next step's 32
        // chunk barriers + B1 before use.
    }
}

// ---------------- fallback GRU (R5): used only if dynamic LDS rejected ---------
__global__ __attribute__((amdgpu_waves_per_eu(4, 4))) __launch_bounds__(1024) void k_gru_fb(
    const float* __restrict__ Whh, const float* __restrict__ Gx,
    const float* __restrict__ Wih, const float* __restrict__ bhh_g,
    const float* __restrict__ Wf, const float* __restrict__ bf_g,
    const float* __restrict__ targets, const unsigned char* __restrict__ fmask,
    const int* __restrict__ flag, float* __restrict__ out)
{
    __shared__ __align__(16) float hq[8 * 268];
    __shared__ float gsum[768];
    __shared__ float tfl[16];
    __shared__ float wtfL[30 * 256];
    __shared__ float WfL[2560];
    const int b = blockIdx.x, tid = threadIdx.x;
    const int kgs = tid & 15, rg = tid >> 4;
    const bool isGate = (tid < 256);
    float bh0 = 0.f, bh1 = 0.f, bh2 = 0.f, hold = 0.f;
    if (isGate) { bh0 = bhh_g[tid]; bh1 = bhh_g[tid + 256]; bh2 = bhh_g[tid + 512]; }
    const bool isProj = (tid >= 256 && tid < 416);
    const int oc = (tid - 256) >> 4, seg = tid & 15;
    float bfc = isProj ? bf_g[oc] : 0.f;
    const bool isWr = isProj && (seg == 15);
    const int int32mode = flag[0];
    for (int e = tid; e < 7680; e += 1024) {
        int cp = e >> 8, jj = e & 255;
        int g = cp / 10, c = cp - g * 10;
        wtfL[e] = Wih[(g * 256 + jj) * 138 + 128 + c];
    }
    for (int e = tid; e < 2560; e += 1024) WfL[e] = Wf[e];
    for (int e = tid; e < 8 * 268; e += 1024) hq[e] = 0.f;
    if (tid < 16) tfl[tid] = 0.f;
    __syncthreads();
    const float4* hbase = (const float4*)&hq[(kgs >> 1) * 268 + kgs * 16];
    const float4* wbase = ((const float4*)Whh) + kgs * 4;
    int tr = 0;
    for (int t = 0; t < 1024; t++) {
        float gxr = 0.f, gxz = 0.f, gxn = 0.f;
        if (isGate) {
            const float* gx = &Gx[((long)t * 32 + b) * 768];
            gxr = gx[tid]; gxz = gx[tid + 256]; gxn = gx[tid + 512];
        }
        float tgt = 0.f; int fmv = 0;
        if (isWr) {
            tgt = targets[((long)b * 1024 + t) * 10 + oc];
            fmv = int32mode ? ((const int*)fmask)[t * 32 + b] : (int)fmask[t * 32 + b];
        }
        float4 hv[4];
#pragma unroll
        for (int q = 0; q < 4; q++) hv[q] = hbase[q];
        float4 sb[3][4];
#pragma unroll
        for (int pq = 0; pq < 3; pq++) {
            int ro = tr + pq; if (ro >= 12) ro -= 12;
            const float4* wp = wbase + (rg * 12 + ro) * 64;
#pragma unroll
            for (int q = 0; q < 4; q++) sb[pq][q] = wp[q];
        }
#pragma unroll
        for (int i = 0; i < 12; i++) {
            const int sl = i % 3;
            int ro = tr + i; if (ro >= 12) ro -= 12;
            float s = 0.f;
#pragma unroll
            for (int q = 0; q < 4; q++) {
                s = fmaf(sb[sl][q].x, hv[q].x, s);
                s = fmaf(sb[sl][q].y, hv[q].y, s);
                s = fmaf(sb[sl][q].z, hv[q].z, s);
                s = fmaf(sb[sl][q].w, hv[q].w, s);
            }
            if (i + 3 < 12) {
                int rn = tr + i + 3; if (rn >= 12) rn -= 12;
                const float4* wp = wbase + (rg * 12 + rn) * 64;
#pragma unroll
                for (int q = 0; q < 4; q++) sb[sl][q] = wp[q];
            }
            s = dpp_add<0x111>(s);
            s = dpp_add<0x112>(s);
            s = dpp_add<0x114>(s);
            s = dpp_add<0x118>(s);
            if (kgs == 15) gsum[rg * 12 + ro] = s;
        }
        __syncthreads();
        if (isGate) {
            float gr = gxr, gz = gxz, gn = gxn;
#pragma unroll
            for (int c = 0; c < 10; c++) {
                float tv = tfl[c];
                gr = fmaf(tv, wtfL[c * 256 + tid], gr);
                gz = fmaf(tv, wtfL[(10 + c) * 256 + tid], gz);
                gn = fmaf(tv, wtfL[(20 + c) * 256 + tid], gn);
            }
            float ar = gsum[tid] + bh0;
            float az = gsum[tid + 256] + bh1;
            float an = gsum[tid + 512] + bh2;
            float r = 1.0f / (1.0f + expf(-(gr + ar)));
            float z = 1.0f / (1.0f + expf(-(gz + az)));
            float n = tanhf(fmaf(r, an, gn));
            float hnew = (1.0f - z) * n + z * hold;
            hold = hnew;
#pragma unroll
            for (int c = 0; c < 8; c++) hq[c * 268 + tid] = hnew;
        }
        __syncthreads();
        if (isProj) {
            const float* hp2 = &hq[(seg >> 1) * 268 + seg * 16];
            const float* wfp = &WfL[oc * 256 + seg * 16];
            float s = 0.f;
#pragma unroll
            for (int i = 0; i < 16; i++) s = fmaf(wfp[i], hp2[i], s);
            s = dpp_add<0x111>(s);
            s = dpp_add<0x112>(s);
            s = dpp_add<0x114>(s);
            s = dpp_add<0x118>(s);
            if (isWr) {
                float o = s + bfc;
                out[((long)b * 1024 + t) * 10 + oc] = o;
                float pred = (o > 0.f) ? 1.f : 0.f;
                tfl[oc] = fmv ? tgt : pred;
            }
        }
        tr++; if (tr == 12) tr = 0;
    }
}

extern "C" void kernel_launch(void* const* d_in, const int* in_sizes, int n_in,
                              void* d_out, int out_size, void* d_ws, size_t ws_size,
                              hipStream_t stream) {
    (void)in_sizes; (void)n_in; (void)out_size; (void)ws_size;
    const float* features = (const float*)d_in[0];
    const float* targets  = (const float*)d_in[1];
    const unsigned char* fmask = (const unsigned char*)d_in[2];
    const float* W1  = (const float*)d_in[3];
    const float* b1  = (const float*)d_in[4];
    const float* g1  = (const float*)d_in[5];
    const float* be1 = (const float*)d_in[6];
    const float* m1  = (const float*)d_in[7];
    const float* v1  = (const float*)d_in[8];
    const float* W2  = (const float*)d_in[9];
    const float* b2  = (const float*)d_in[10];
    const float* g2  = (const float*)d_in[11];
    const float* be2 = (const float*)d_in[12];
    const float* m2  = (const float*)d_in[13];
    const float* v2  = (const float*)d_in[14];
    const float* W3  = (const float*)d_in[15];
    const float* b3  = (const float*)d_in[16];
    const float* g3  = (const float*)d_in[17];
    const float* be3 = (const float*)d_in[18];
    const float* m3  = (const float*)d_in[19];
    const float* v3  = (const float*)d_in[20];
    const float* Wih = (const float*)d_in[21];
    const float* Whh = (const float*)d_in[22];
    const float* bih = (const float*)d_in[23];
    const float* bhh = (const float*)d_in[24];
    const float* Wf  = (const float*)d_in[25];
    const float* bf  = (const float*)d_in[26];

    char* w = (char*)d_ws;
    float* WhhTs = (float*)(w + 0);                     // 786432 B
    float* WxT = (float*)(w + 786432);                  // 393216 B
    float* W2T = (float*)(w + 1179648);                 // 1638400 B
    float* W3T = (float*)(w + 2818048);                 // 1638400 B
    int*   flag = (int*)(w + 4456448);                  // 512 B slot
    float* X1  = (float*)(w + 4456960);                 // 128 MB; reused as Gx after conv2
    float* Gx  = X1;
    float* X2  = (float*)(w + 4456960 + 134217728);     // 32 MB
    float* F   = (float*)(w + 4456960 + 134217728 + 33554432); // 16 MB
    float* out = (float*)d_out;

    const int GRU_LDS = (36864 + 256 + 768 + 16) * 4;   // 151616 B
    hipError_t rc = hipFuncSetAttribute((const void*)k_gru,
        hipFuncAttributeMaxDynamicSharedMemorySize, GRU_LDS);

    k_prep<<<1600, 256, 0, stream>>>(Wih, Whh, W2, W3, fmask, WhhTs, WxT, W2T, W3T, flag);
    k_conv1<<<8192, 256, 0, stream>>>(features, W1, b1, g1, be1, m1, v1, X1);
    k_conv2<<<4096, 256, 0, stream>>>(X1, W2T, b2, g2, be2, m2, v2, X2);
    k_conv3<<<4096, 256, 0, stream>>>(X2, W3T, b3, g3, be3, m3, v3, F);
    k_gemm<<<1536, 256, 0, stream>>>(F, WxT, bih, Gx);
    if (rc == hipSuccess) {
        k_gru<<<32, 1024, GRU_LDS, stream>>>(WhhTs, Gx, Wih, bhh, Wf, bf,
                                             targets, fmask, flag, out);
    } else {
        k_gru_fb<<<32, 1024, 0, stream>>>(Whh, Gx, Wih, bhh, Wf, bf,
                                          targets, fmask, flag, out);
    }
}